// Round 9
// baseline (509.694 us; speedup 1.0000x reference)
//
#include <hip/hip_runtime.h>
#include <cstdint>

#define NROWS 131072
#define HD    128      // H == IN == 128
#define NDIM  512      // 4*H
#define OUTQ  16777216 // NROWS*HD

using bf16x8 = __attribute__((ext_vector_type(8))) short;
using f32x4  = __attribute__((ext_vector_type(4))) float;

__device__ __forceinline__ uint32_t bf16rne(float f) {
  uint32_t u = __builtin_bit_cast(uint32_t, f);
  return (u + 0x7fffu + ((u >> 16) & 1u)) >> 16;
}

__device__ __forceinline__ float tanhf_fast(float v) {
  float a = __builtin_fabsf(v);
  float e = __expf(-2.0f * a);
  float t = (1.0f - e) * __builtin_amdgcn_rcpf(1.0f + e);
  return v < 0.0f ? -t : t;
}

__device__ __forceinline__ f32x4 ldv(const float* p) {
  return *reinterpret_cast<const f32x4*>(p);
}

// Pack Wf[k][n] = W[k][n] + (k>=128 ? r[k-128][n] : 0) as bf16 fragments.
// Frag (g*8 + t)*8 + s (1 KB each): element j of lane l =
//   Wf[s*32 + (l>>4)*8 + j][gate g, col t*16 + (l&15)].
// Serves as the MFMA A-operand of Wf^T (rows = gate cols).
__global__ __launch_bounds__(256) void pack_weights(
    const float* __restrict__ W, const float* __restrict__ r,
    uint16_t* __restrict__ Bp) {
  int idx = blockIdx.x * 256 + threadIdx.x;   // 16384 frags total
  int l  = idx & 63;
  int ts = idx >> 6;
  int s  = ts & 7;
  int t  = ts >> 3;
  int ncol  = t * 16 + (l & 15);
  int kbase = s * 32 + ((l >> 4) << 3);
  uint32_t w[4];
#pragma unroll
  for (int jj = 0; jj < 4; ++jj) {
    int k0 = kbase + 2 * jj;
    float v0 = W[k0 * NDIM + ncol];
    float v1 = W[(k0 + 1) * NDIM + ncol];
    if (k0 >= 128)     v0 += r[(k0 - 128) * NDIM + ncol];
    if (k0 + 1 >= 128) v1 += r[(k0 + 1 - 128) * NDIM + ncol];
    w[jj] = bf16rne(v0) | (bf16rne(v1) << 16);
  }
  reinterpret_cast<uint4*>(Bp)[idx] = make_uint4(w[0], w[1], w[2], w[3]);
}

// One wave per 16 batch rows; 2 waves/block; no LDS, no barriers.
// Weights read directly from the L2-resident packed buffer (16B/lane,
// fully coalesced 1KB per instruction).
__global__ __launch_bounds__(128, 8) void slstm_fused(
    const float* __restrict__ x,  const float* __restrict__ h,
    const float* __restrict__ cs, const float* __restrict__ ns,
    const float* __restrict__ ms, const float* __restrict__ bias,
    const uint16_t* __restrict__ Bp, float* __restrict__ out) {
  const int tid  = threadIdx.x;
  const int wave = tid >> 6;
  const int lane = tid & 63;
  const int l15  = lane & 15;
  const int lg   = lane >> 4;

  // Transposed D layout: lane owns batchrow and gate-cols 16t+4*lg+rr.
  const int    myrow = blockIdx.x * 32 + wave * 16 + l15;
  const size_t rbase = (size_t)myrow * HD;
  const int    jb    = lg * 4;

  // c/n/m tile-0 prefetch
  f32x4 cvA = ldv(cs + rbase + jb);
  f32x4 nvA = ldv(ns + rbase + jb);
  f32x4 mvA = ldv(ms + rbase + jb);
  f32x4 cvB = {0,0,0,0}, nvB = {0,0,0,0}, mvB = {0,0,0,0};

  // A/B fragments loaded directly from global:
  // lane needs xh[myrow][s*32 + lg*8 + j], j=0..7 -> contiguous 32B.
  bf16x8 a[8];
#pragma unroll
  for (int s = 0; s < 8; ++s) {
    const float* src = (s < 4 ? x : h) + rbase + ((s & 3) * 32 + lg * 8);
    f32x4 v0 = ldv(src);
    f32x4 v1 = ldv(src + 4);
    bf16x8 pk;
    pk[0] = (short)bf16rne(v0[0]);
    pk[1] = (short)bf16rne(v0[1]);
    pk[2] = (short)bf16rne(v0[2]);
    pk[3] = (short)bf16rne(v0[3]);
    pk[4] = (short)bf16rne(v1[0]);
    pk[5] = (short)bf16rne(v1[1]);
    pk[6] = (short)bf16rne(v1[2]);
    pk[7] = (short)bf16rne(v1[3]);
    a[s] = pk;
  }

  const bf16x8* __restrict__ Bf = reinterpret_cast<const bf16x8*>(Bp);

  // ---- 8 column tiles, fully unrolled, self-paced (no barriers) ----
#pragma unroll
  for (int t = 0; t < 8; ++t) {
    if (t < 7) {       // prefetch c/n/m for t+1
      const size_t pp = rbase + jb + 16 * (t + 1);
      cvB = ldv(cs + pp);
      nvB = ldv(ns + pp);
      mvB = ldv(ms + pp);
    }
    const int j0 = jb + 16 * t;
    const f32x4 bI = ldv(bias + j0);
    const f32x4 bF = ldv(bias + 128 + j0);
    const f32x4 bZ = ldv(bias + 256 + j0);
    const f32x4 bO = ldv(bias + 384 + j0);

    f32x4 accI = {0.f, 0.f, 0.f, 0.f};
    f32x4 accF = {0.f, 0.f, 0.f, 0.f};
    f32x4 accZ = {0.f, 0.f, 0.f, 0.f};
    f32x4 accO = {0.f, 0.f, 0.f, 0.f};
#pragma unroll
    for (int s = 0; s < 8; ++s) {
      accI = __builtin_amdgcn_mfma_f32_16x16x32_bf16(Bf[(size_t)(((0 * 8 + t) * 8) + s) * 64 + lane], a[s], accI, 0, 0, 0);
      accF = __builtin_amdgcn_mfma_f32_16x16x32_bf16(Bf[(size_t)(((1 * 8 + t) * 8) + s) * 64 + lane], a[s], accF, 0, 0, 0);
      accZ = __builtin_amdgcn_mfma_f32_16x16x32_bf16(Bf[(size_t)(((2 * 8 + t) * 8) + s) * 64 + lane], a[s], accZ, 0, 0, 0);
      accO = __builtin_amdgcn_mfma_f32_16x16x32_bf16(Bf[(size_t)(((3 * 8 + t) * 8) + s) * 64 + lane], a[s], accO, 0, 0, 0);
    }

    f32x4 hn, cn, nn, mn;
#pragma unroll
    for (int rr = 0; rr < 4; ++rr) {
      float i_raw = accI[rr] + bI[rr];
      float f_raw = accF[rr] + bF[rr];
      float z_raw = accZ[rr] + bZ[rr];
      float o_raw = accO[rr] + bO[rr];
      float ef  = __expf(-f_raw);
      float den = 1.0f + ef;
      float fg  = __builtin_amdgcn_rcpf(den);   // sigmoid(f_raw)
      float lgf = -__logf(den);                 // log sigmoid(f_raw)
      float mnv = fmaxf(lgf + mvA[rr], i_raw);  // m_new
      float ip  = __expf(i_raw - mnv);          // i'
      float zt  = tanhf_fast(z_raw);
      float og  = __builtin_amdgcn_rcpf(1.0f + __expf(-o_raw));
      float cnv = fg * cvA[rr] + ip * zt;       // c_new (f' == f per source)
      float nnv = fg * nvA[rr] + ip;            // n_new
      hn[rr] = og * tanhf_fast(cnv * __builtin_amdgcn_rcpf(nnv));
      cn[rr] = cnv;
      nn[rr] = nnv;
      mn[rr] = mnv;
    }
    const size_t p = rbase + jb + 16 * t;
    *reinterpret_cast<f32x4*>(out + p)            = hn;
    *reinterpret_cast<f32x4*>(out + OUTQ + p)     = cn;
    *reinterpret_cast<f32x4*>(out + 2 * OUTQ + p) = nn;
    *reinterpret_cast<f32x4*>(out + 3 * OUTQ + p) = mn;

    cvA = cvB; nvA = nvB; mvA = mvB;
  }
}

extern "C" void kernel_launch(void* const* d_in, const int* in_sizes, int n_in,
                              void* d_out, int out_size, void* d_ws, size_t ws_size,
                              hipStream_t stream) {
  const float* x = (const float*)d_in[0];
  const float* h = (const float*)d_in[1];
  const float* c = (const float*)d_in[2];
  const float* n = (const float*)d_in[3];
  const float* m = (const float*)d_in[4];
  const float* W = (const float*)d_in[5];
  const float* r = (const float*)d_in[6];
  const float* b = (const float*)d_in[7];
  uint16_t* Bp = (uint16_t*)d_ws;   // 256 KB packed bf16 weights

  pack_weights<<<64, 256, 0, stream>>>(W, r, Bp);
  slstm_fused<<<NROWS / 32, 128, 0, stream>>>(x, h, c, n, m, b, Bp, (float*)d_out);
}

// Round 10
// 415.892 us; speedup vs baseline: 1.2255x; 1.2255x over previous
//
#include <hip/hip_runtime.h>
#include <cstdint>

#define NROWS 131072
#define HD    128      // H == IN == 128
#define NDIM  512      // 4*H
#define OUTQ  16777216 // NROWS*HD

using bf16x8 = __attribute__((ext_vector_type(8))) short;
using f32x4  = __attribute__((ext_vector_type(4))) float;

__device__ __forceinline__ uint32_t bf16rne(float f) {
  uint32_t u = __builtin_bit_cast(uint32_t, f);
  return (u + 0x7fffu + ((u >> 16) & 1u)) >> 16;
}

__device__ __forceinline__ float unpk_lo(uint32_t p) {
  return __builtin_bit_cast(float, p << 16);
}
__device__ __forceinline__ float unpk_hi(uint32_t p) {
  return __builtin_bit_cast(float, p & 0xffff0000u);
}

__device__ __forceinline__ float tanhf_fast(float v) {
  float a = __builtin_fabsf(v);
  float e = __expf(-2.0f * a);
  float t = (1.0f - e) * __builtin_amdgcn_rcpf(1.0f + e);
  return v < 0.0f ? -t : t;
}

__device__ __forceinline__ f32x4 ldv(const float* p) {
  return *reinterpret_cast<const f32x4*>(p);
}

// Async global->LDS DMA, 16B per lane. LDS dest = uniform base + lane*16.
#define ASYNC16(g, l)                                                        \
  __builtin_amdgcn_global_load_lds(                                          \
      (const __attribute__((address_space(1))) void*)(g),                    \
      (__attribute__((address_space(3))) void*)(l), 16, 0, 0)

// Pack Wf[k][n] = W[k][n] + (k>=128 ? r[k-128][n] : 0) as bf16 fragments.
// Frag (g*8 + t)*8 + s (1 KB each): element j of lane l =
//   Wf[s*32 + (l>>4)*8 + j][gate g, col t*16 + (l&15)].
__global__ __launch_bounds__(256) void pack_weights(
    const float* __restrict__ W, const float* __restrict__ r,
    uint16_t* __restrict__ Bp) {
  int idx = blockIdx.x * 256 + threadIdx.x;   // 16384 frags total
  int l  = idx & 63;
  int ts = idx >> 6;
  int s  = ts & 7;
  int t  = ts >> 3;
  int ncol  = t * 16 + (l & 15);
  int kbase = s * 32 + ((l >> 4) << 3);
  uint32_t w[4];
#pragma unroll
  for (int jj = 0; jj < 4; ++jj) {
    int k0 = kbase + 2 * jj;
    float v0 = W[k0 * NDIM + ncol];
    float v1 = W[(k0 + 1) * NDIM + ncol];
    if (k0 >= 128)     v0 += r[(k0 - 128) * NDIM + ncol];
    if (k0 + 1 >= 128) v1 += r[(k0 + 1 - 128) * NDIM + ncol];
    w[jj] = bf16rne(v0) | (bf16rne(v1) << 16);
  }
  reinterpret_cast<uint4*>(Bp)[idx] = make_uint4(w[0], w[1], w[2], w[3]);
}

__global__ __launch_bounds__(256, 3) void slstm_fused(
    const float* __restrict__ x,  const float* __restrict__ h,
    const float* __restrict__ cs, const float* __restrict__ ns,
    const float* __restrict__ ms, const float* __restrict__ bias,
    const uint16_t* __restrict__ Bp, float* __restrict__ out) {
  // 32 KB LDS, time-shared: (1) weight tile buffer during the GEMM loop,
  // (2) output transpose buffer for coalesced 1KB-per-wave stores.
  __shared__ __align__(16) char smem[32768];
  const int tid  = threadIdx.x;
  const int wave = tid >> 6;
  const int lane = tid & 63;
  const int row0 = blockIdx.x * 64;
  const int l15  = lane & 15;
  const int lg   = lane >> 4;

  // Transposed D layout: lane owns batchrow = wave*16 + l15, gate-cols
  // 16*t + 4*lg + rr -> epilogue I/O is f32x4 (64B per 4-lane group).
  const int    myrow = row0 + wave * 16 + l15;
  const size_t rbase = (size_t)myrow * HD;
  const int    jb    = lg * 4;

  // c/n/m tile-0 prefetch (longest issue-to-use distance)
  f32x4 cvA = ldv(cs + rbase + jb);
  f32x4 nvA = ldv(ns + rbase + jb);
  f32x4 mvA = ldv(ms + rbase + jb);
  f32x4 cvB = {0,0,0,0}, nvB = {0,0,0,0}, mvB = {0,0,0,0};

  // DMA weight tile 0: wave w stages gate w, k-steps 0..7 (wave-private 8KB)
  const char* wBytes = (const char*)Bp;
  {
    const char* gsrc = wBytes + (((size_t)(wave * 8 + 0) * 8) << 10) + (lane << 4);
    char* ldst = smem + (wave << 13);
#pragma unroll
    for (int k = 0; k < 8; ++k)
      ASYNC16(gsrc + (k << 10), ldst + (k << 10));
  }

  // A/B fragments direct from global: xh[myrow][s*32+lg*8+j] = 32B contig.
  bf16x8 a[8];
#pragma unroll
  for (int s = 0; s < 8; ++s) {
    const float* src = (s < 4 ? x : h) + rbase + ((s & 3) * 32 + lg * 8);
    f32x4 v0 = ldv(src);
    f32x4 v1 = ldv(src + 4);
    bf16x8 pk;
    pk[0] = (short)bf16rne(v0[0]);
    pk[1] = (short)bf16rne(v0[1]);
    pk[2] = (short)bf16rne(v0[2]);
    pk[3] = (short)bf16rne(v0[3]);
    pk[4] = (short)bf16rne(v1[0]);
    pk[5] = (short)bf16rne(v1[1]);
    pk[6] = (short)bf16rne(v1[2]);
    pk[7] = (short)bf16rne(v1[3]);
    a[s] = pk;
  }

  // Per-tile outputs, bf16-packed (2 VGPR/tile/array = 64 total; static idx)
  uint32_t pH[8][2], pC[8][2], pN[8][2], pM[8][2];

  // ---- 8 column tiles, fully unrolled; R4's proven 2-barrier scheme ----
#pragma unroll
  for (int t = 0; t < 8; ++t) {
    __syncthreads();   // barrier A: vm drain -> tile t weights visible

    if (t < 7) {       // prefetch c/n/m for t+1
      const size_t pp = rbase + jb + 16 * (t + 1);
      cvB = ldv(cs + pp);
      nvB = ldv(ns + pp);
      mvB = ldv(ms + pp);
    }
    const int j0 = jb + 16 * t;
    const f32x4 bI = ldv(bias + j0);
    const f32x4 bF = ldv(bias + 128 + j0);
    const f32x4 bZ = ldv(bias + 256 + j0);
    const f32x4 bO = ldv(bias + 384 + j0);

    f32x4 accI = {0.f, 0.f, 0.f, 0.f};
    f32x4 accF = {0.f, 0.f, 0.f, 0.f};
    f32x4 accZ = {0.f, 0.f, 0.f, 0.f};
    f32x4 accO = {0.f, 0.f, 0.f, 0.f};
#pragma unroll
    for (int s = 0; s < 8; ++s) {
      const int lo = lane << 4;
      bf16x8 wI = *reinterpret_cast<const bf16x8*>(smem + ((0 * 8 + s) << 10) + lo);
      bf16x8 wF = *reinterpret_cast<const bf16x8*>(smem + ((1 * 8 + s) << 10) + lo);
      bf16x8 wZ = *reinterpret_cast<const bf16x8*>(smem + ((2 * 8 + s) << 10) + lo);
      bf16x8 wO = *reinterpret_cast<const bf16x8*>(smem + ((3 * 8 + s) << 10) + lo);
      accI = __builtin_amdgcn_mfma_f32_16x16x32_bf16(wI, a[s], accI, 0, 0, 0);
      accF = __builtin_amdgcn_mfma_f32_16x16x32_bf16(wF, a[s], accF, 0, 0, 0);
      accZ = __builtin_amdgcn_mfma_f32_16x16x32_bf16(wZ, a[s], accZ, 0, 0, 0);
      accO = __builtin_amdgcn_mfma_f32_16x16x32_bf16(wO, a[s], accO, 0, 0, 0);
    }
    __syncthreads();   // barrier B: all waves done reading tile t weights

    if (t < 7) {       // DMA tile t+1; latency hides under epilogue
      const char* gsrc = wBytes + (((size_t)(wave * 8 + (t + 1)) * 8) << 10) + (lane << 4);
      char* ldst = smem + (wave << 13);
#pragma unroll
      for (int k = 0; k < 8; ++k)
        ASYNC16(gsrc + (k << 10), ldst + (k << 10));
    }

    float hn[4], cn[4], nn[4], mn[4];
#pragma unroll
    for (int rr = 0; rr < 4; ++rr) {
      float i_raw = accI[rr] + bI[rr];
      float f_raw = accF[rr] + bF[rr];
      float z_raw = accZ[rr] + bZ[rr];
      float o_raw = accO[rr] + bO[rr];
      float ef  = __expf(-f_raw);
      float den = 1.0f + ef;
      float fg  = __builtin_amdgcn_rcpf(den);   // sigmoid(f_raw)
      float lgf = -__logf(den);                 // log sigmoid(f_raw)
      float mnv = fmaxf(lgf + mvA[rr], i_raw);  // m_new
      float ip  = __expf(i_raw - mnv);          // i'
      float zt  = tanhf_fast(z_raw);
      float og  = __builtin_amdgcn_rcpf(1.0f + __expf(-o_raw));
      float cnv = fg * cvA[rr] + ip * zt;       // c_new (f' == f per source)
      float nnv = fg * nvA[rr] + ip;            // n_new
      hn[rr] = og * tanhf_fast(cnv * __builtin_amdgcn_rcpf(nnv));
      cn[rr] = cnv;
      nn[rr] = nnv;
      mn[rr] = mnv;
    }
    pH[t][0] = bf16rne(hn[0]) | (bf16rne(hn[1]) << 16);
    pH[t][1] = bf16rne(hn[2]) | (bf16rne(hn[3]) << 16);
    pC[t][0] = bf16rne(cn[0]) | (bf16rne(cn[1]) << 16);
    pC[t][1] = bf16rne(cn[2]) | (bf16rne(cn[3]) << 16);
    pN[t][0] = bf16rne(nn[0]) | (bf16rne(nn[1]) << 16);
    pN[t][1] = bf16rne(nn[2]) | (bf16rne(nn[3]) << 16);
    pM[t][0] = bf16rne(mn[0]) | (bf16rne(mn[1]) << 16);
    pM[t][1] = bf16rne(mn[2]) | (bf16rne(mn[3]) << 16);

    cvA = cvB; nvA = nvB; mvA = mvB;
  }

  // ---- store phase: unpack -> LDS transpose -> coalesced plain stores ----
  // Region = one 64x128 f32 array (32 KB); 4 rounds (h,c,n,m).
  const int srow = wave * 16 + l15;                 // 0..63
  const int wswz = (l15 & 7) << 4;                  // srow&7 == l15&7
#define STORE_ROUND(P, AOFF)                                                 \
  {                                                                          \
    _Pragma("unroll")                                                        \
    for (int t = 0; t < 8; ++t) {                                            \
      int addr = (srow * 512 + (jb + 16 * t) * 4) ^ wswz;                    \
      f32x4 v;                                                               \
      v[0] = unpk_lo(P[t][0]); v[1] = unpk_hi(P[t][0]);                      \
      v[2] = unpk_lo(P[t][1]); v[3] = unpk_hi(P[t][1]);                      \
      *reinterpret_cast<f32x4*>(smem + addr) = v;                            \
    }                                                                        \
    __syncthreads();                                                         \
    _Pragma("unroll")                                                        \
    for (int i = 0; i < 8; ++i) {                                            \
      int flat = (i * 256 + tid) * 4;                                        \
      int row  = flat >> 7;                                                  \
      f32x4 v  = *reinterpret_cast<const f32x4*>(                            \
          smem + ((flat * 4) ^ ((row & 7) << 4)));                           \
      *reinterpret_cast<f32x4*>(out + (AOFF) + (size_t)row0 * HD + flat) = v;\
    }                                                                        \
    __syncthreads();                                                         \
  }

  STORE_ROUND(pH, 0)
  STORE_ROUND(pC, OUTQ)
  STORE_ROUND(pN, 2 * OUTQ)
  STORE_ROUND(pM, 3 * OUTQ)
#undef STORE_ROUND
}

extern "C" void kernel_launch(void* const* d_in, const int* in_sizes, int n_in,
                              void* d_out, int out_size, void* d_ws, size_t ws_size,
                              hipStream_t stream) {
  const float* x = (const float*)d_in[0];
  const float* h = (const float*)d_in[1];
  const float* c = (const float*)d_in[2];
  const float* n = (const float*)d_in[3];
  const float* m = (const float*)d_in[4];
  const float* W = (const float*)d_in[5];
  const float* r = (const float*)d_in[6];
  const float* b = (const float*)d_in[7];
  uint16_t* Bp = (uint16_t*)d_ws;   // 256 KB packed bf16 weights

  pack_weights<<<64, 256, 0, stream>>>(W, r, Bp);
  slstm_fused<<<NROWS / 64, 256, 0, stream>>>(x, h, c, n, m, b, Bp, (float*)d_out);
}

// Round 11
// 149.217 us; speedup vs baseline: 3.4158x; 2.7872x over previous
//
#include <hip/hip_runtime.h>
#include <cstdint>

#define NROWS 131072
#define HD    128      // H == IN == 128
#define NDIM  512      // 4*H
#define OUTQ  16777216 // NROWS*HD

using bf16x8 = __attribute__((ext_vector_type(8))) short;
using f32x4  = __attribute__((ext_vector_type(4))) float;

__device__ __forceinline__ uint32_t bf16rne(float f) {
  uint32_t u = __builtin_bit_cast(uint32_t, f);
  return (u + 0x7fffu + ((u >> 16) & 1u)) >> 16;
}

__device__ __forceinline__ float tanhf_fast(float v) {
  float a = __builtin_fabsf(v);
  float e = __expf(-2.0f * a);
  float t = (1.0f - e) * __builtin_amdgcn_rcpf(1.0f + e);
  return v < 0.0f ? -t : t;
}

__device__ __forceinline__ f32x4 ldv(const float* p) {
  return *reinterpret_cast<const f32x4*>(p);
}

// Async global->LDS DMA, 16B per lane. LDS dest = uniform base + lane*16.
#define ASYNC16(g, l)                                                        \
  __builtin_amdgcn_global_load_lds(                                          \
      (const __attribute__((address_space(1))) void*)(g),                    \
      (__attribute__((address_space(3))) void*)(l), 16, 0, 0)

// Pack Wf[k][n] = W[k][n] + (k>=128 ? r[k-128][n] : 0) as bf16 A-fragments
// of Wf^T with a PERMUTED row->gate-col map. Half-step u = t2*2+p of
// mega-tile t2 (32 gate cols): A-row m (0..15) maps to within-gate col
//   t2*32 + (m>>2)*8 + p*4 + (m&3)
// so a lane's D fragment (m = 4*lg + rr over p=0,1) covers the 8
// CONTIGUOUS cols t2*32 + lg*8 .. +7  -> full-line epilogue I/O.
// Frag (g*8 + u)*8 + s (1 KB): elem j of lane l = Wf[s*32+(l>>4)*8+j][ncol].
__global__ __launch_bounds__(256) void pack_weights(
    const float* __restrict__ W, const float* __restrict__ r,
    uint16_t* __restrict__ Bp) {
  int idx = blockIdx.x * 256 + threadIdx.x;   // 16384 frags total
  int l  = idx & 63;
  int ts = idx >> 6;
  int s  = ts & 7;
  int t  = ts >> 3;          // 0..31 = g*8 + u
  int g  = t >> 3;
  int u  = t & 7;
  int t2 = u >> 1;
  int p  = u & 1;
  int m  = l & 15;           // A-row index held by this lane
  int ncol  = g * 128 + t2 * 32 + ((m >> 2) << 3) + p * 4 + (m & 3);
  int kbase = s * 32 + ((l >> 4) << 3);
  uint32_t w[4];
#pragma unroll
  for (int jj = 0; jj < 4; ++jj) {
    int k0 = kbase + 2 * jj;
    float v0 = W[k0 * NDIM + ncol];
    float v1 = W[(k0 + 1) * NDIM + ncol];
    if (k0 >= 128)     v0 += r[(k0 - 128) * NDIM + ncol];
    if (k0 + 1 >= 128) v1 += r[(k0 + 1 - 128) * NDIM + ncol];
    w[jj] = bf16rne(v0) | (bf16rne(v1) << 16);
  }
  reinterpret_cast<uint4*>(Bp)[idx] = make_uint4(w[0], w[1], w[2], w[3]);
}

__global__ __launch_bounds__(256, 3) void slstm_fused(
    const float* __restrict__ x,  const float* __restrict__ h,
    const float* __restrict__ cs, const float* __restrict__ ns,
    const float* __restrict__ ms, const float* __restrict__ bias,
    const uint16_t* __restrict__ Bp, float* __restrict__ out) {
  // LDS = one 32 KB half-step weight buffer (32 frags x 1 KB).
  __shared__ __align__(16) char smem[32768];
  const int tid  = threadIdx.x;
  const int wave = tid >> 6;
  const int lane = tid & 63;
  const int row0 = blockIdx.x * 64;
  const int l15  = lane & 15;
  const int lg   = lane >> 4;

  const int    myrow = row0 + wave * 16 + l15;
  const size_t rbase = (size_t)myrow * HD;
  const int    jb8   = lg * 8;   // lane's contiguous 8-col base in mega-tile

  const char* wBytes = (const char*)Bp;
  // DMA half-step 0: wave w stages gate w, k-steps 0..7 (wave-private 8KB)
  {
    const char* gsrc = wBytes + (((size_t)(wave * 8 + 0) * 8) << 10) + (lane << 4);
    char* ldst = smem + (wave << 13);
#pragma unroll
    for (int k = 0; k < 8; ++k)
      ASYNC16(gsrc + (k << 10), ldst + (k << 10));
  }

  // B-operand fragments direct from global: xh[myrow][s*32+lg*8+j], 32B contig.
  bf16x8 a[8];
#pragma unroll
  for (int s = 0; s < 8; ++s) {
    const float* src = (s < 4 ? x : h) + rbase + ((s & 3) * 32 + lg * 8);
    f32x4 v0 = ldv(src);
    f32x4 v1 = ldv(src + 4);
    bf16x8 pk;
    pk[0] = (short)bf16rne(v0[0]);
    pk[1] = (short)bf16rne(v0[1]);
    pk[2] = (short)bf16rne(v0[2]);
    pk[3] = (short)bf16rne(v0[3]);
    pk[4] = (short)bf16rne(v1[0]);
    pk[5] = (short)bf16rne(v1[1]);
    pk[6] = (short)bf16rne(v1[2]);
    pk[7] = (short)bf16rne(v1[3]);
    a[s] = pk;
  }

  // ---- 4 mega-tiles x 2 half-steps, fully unrolled ----
#pragma unroll
  for (int t2 = 0; t2 < 4; ++t2) {
    const int cb = t2 * 32 + jb8;        // lane's global col base (within H)

    __syncthreads();   // half-step 2*t2 weights (p=0) visible

    // c/n/m loads for this mega-tile: 2 x f32x4 per array, 128B/row-group.
    const f32x4 cvLo = ldv(cs + rbase + cb), cvHi = ldv(cs + rbase + cb + 4);
    const f32x4 nvLo = ldv(ns + rbase + cb), nvHi = ldv(ns + rbase + cb + 4);
    const f32x4 mvLo = ldv(ms + rbase + cb), mvHi = ldv(ms + rbase + cb + 4);

    f32x4 accI0 = {0,0,0,0}, accF0 = {0,0,0,0}, accZ0 = {0,0,0,0}, accO0 = {0,0,0,0};
#pragma unroll
    for (int s = 0; s < 8; ++s) {
      const int lo = lane << 4;
      bf16x8 wI = *reinterpret_cast<const bf16x8*>(smem + ((0 * 8 + s) << 10) + lo);
      bf16x8 wF = *reinterpret_cast<const bf16x8*>(smem + ((1 * 8 + s) << 10) + lo);
      bf16x8 wZ = *reinterpret_cast<const bf16x8*>(smem + ((2 * 8 + s) << 10) + lo);
      bf16x8 wO = *reinterpret_cast<const bf16x8*>(smem + ((3 * 8 + s) << 10) + lo);
      accI0 = __builtin_amdgcn_mfma_f32_16x16x32_bf16(wI, a[s], accI0, 0, 0, 0);
      accF0 = __builtin_amdgcn_mfma_f32_16x16x32_bf16(wF, a[s], accF0, 0, 0, 0);
      accZ0 = __builtin_amdgcn_mfma_f32_16x16x32_bf16(wZ, a[s], accZ0, 0, 0, 0);
      accO0 = __builtin_amdgcn_mfma_f32_16x16x32_bf16(wO, a[s], accO0, 0, 0, 0);
    }
    __syncthreads();   // done reading p=0 weights

    {  // DMA half-step 2*t2+1 (p=1)
      const char* gsrc = wBytes + (((size_t)(wave * 8 + (2 * t2 + 1)) * 8) << 10) + (lane << 4);
      char* ldst = smem + (wave << 13);
#pragma unroll
      for (int k = 0; k < 8; ++k)
        ASYNC16(gsrc + (k << 10), ldst + (k << 10));
    }
    __syncthreads();   // p=1 weights visible

    // biases (L2-hot; covered by MFMA p=1 before use)
    const f32x4 bIlo = ldv(bias + cb),        bIhi = ldv(bias + cb + 4);
    const f32x4 bFlo = ldv(bias + 128 + cb),  bFhi = ldv(bias + 128 + cb + 4);
    const f32x4 bZlo = ldv(bias + 256 + cb),  bZhi = ldv(bias + 256 + cb + 4);
    const f32x4 bOlo = ldv(bias + 384 + cb),  bOhi = ldv(bias + 384 + cb + 4);

    f32x4 accI1 = {0,0,0,0}, accF1 = {0,0,0,0}, accZ1 = {0,0,0,0}, accO1 = {0,0,0,0};
#pragma unroll
    for (int s = 0; s < 8; ++s) {
      const int lo = lane << 4;
      bf16x8 wI = *reinterpret_cast<const bf16x8*>(smem + ((0 * 8 + s) << 10) + lo);
      bf16x8 wF = *reinterpret_cast<const bf16x8*>(smem + ((1 * 8 + s) << 10) + lo);
      bf16x8 wZ = *reinterpret_cast<const bf16x8*>(smem + ((2 * 8 + s) << 10) + lo);
      bf16x8 wO = *reinterpret_cast<const bf16x8*>(smem + ((3 * 8 + s) << 10) + lo);
      accI1 = __builtin_amdgcn_mfma_f32_16x16x32_bf16(wI, a[s], accI1, 0, 0, 0);
      accF1 = __builtin_amdgcn_mfma_f32_16x16x32_bf16(wF, a[s], accF1, 0, 0, 0);
      accZ1 = __builtin_amdgcn_mfma_f32_16x16x32_bf16(wZ, a[s], accZ1, 0, 0, 0);
      accO1 = __builtin_amdgcn_mfma_f32_16x16x32_bf16(wO, a[s], accO1, 0, 0, 0);
    }
    __syncthreads();   // done reading p=1 weights

    if (t2 < 3) {  // DMA next mega-tile's p=0; latency hides under epilogue
      const char* gsrc = wBytes + (((size_t)(wave * 8 + (2 * t2 + 2)) * 8) << 10) + (lane << 4);
      char* ldst = smem + (wave << 13);
#pragma unroll
      for (int k = 0; k < 8; ++k)
        ASYNC16(gsrc + (k << 10), ldst + (k << 10));
    }

    // ---- epilogue: 8 contiguous cols/lane -> 2 full-line f32x4 IOs each ----
    f32x4 hnLo, hnHi, cnLo, cnHi, nnLo, nnHi, mnLo, mnHi;
#pragma unroll
    for (int d = 0; d < 8; ++d) {
      const int pp = d >> 2, rr = d & 3;
      const float i_raw = (pp ? accI1[rr] : accI0[rr]) + (pp ? bIhi[rr] : bIlo[rr]);
      const float f_raw = (pp ? accF1[rr] : accF0[rr]) + (pp ? bFhi[rr] : bFlo[rr]);
      const float z_raw = (pp ? accZ1[rr] : accZ0[rr]) + (pp ? bZhi[rr] : bZlo[rr]);
      const float o_raw = (pp ? accO1[rr] : accO0[rr]) + (pp ? bOhi[rr] : bOlo[rr]);
      const float cV = pp ? cvHi[rr] : cvLo[rr];
      const float nV = pp ? nvHi[rr] : nvLo[rr];
      const float mV = pp ? mvHi[rr] : mvLo[rr];
      float ef  = __expf(-f_raw);
      float den = 1.0f + ef;
      float fg  = __builtin_amdgcn_rcpf(den);   // sigmoid(f_raw)
      float lgf = -__logf(den);                 // log sigmoid(f_raw)
      float mnv = fmaxf(lgf + mV, i_raw);       // m_new
      float ip  = __expf(i_raw - mnv);          // i'
      float zt  = tanhf_fast(z_raw);
      float og  = __builtin_amdgcn_rcpf(1.0f + __expf(-o_raw));
      float cnv = fg * cV + ip * zt;            // c_new (f' == f per source)
      float nnv = fg * nV + ip;                 // n_new
      float hnv = og * tanhf_fast(cnv * __builtin_amdgcn_rcpf(nnv));
      if (pp == 0) { hnLo[rr] = hnv; cnLo[rr] = cnv; nnLo[rr] = nnv; mnLo[rr] = mnv; }
      else         { hnHi[rr] = hnv; cnHi[rr] = cnv; nnHi[rr] = nnv; mnHi[rr] = mnv; }
    }
    const size_t pbase = rbase + cb;
    *reinterpret_cast<f32x4*>(out + pbase)                = hnLo;
    *reinterpret_cast<f32x4*>(out + pbase + 4)            = hnHi;
    *reinterpret_cast<f32x4*>(out + OUTQ + pbase)         = cnLo;
    *reinterpret_cast<f32x4*>(out + OUTQ + pbase + 4)     = cnHi;
    *reinterpret_cast<f32x4*>(out + 2 * OUTQ + pbase)     = nnLo;
    *reinterpret_cast<f32x4*>(out + 2 * OUTQ + pbase + 4) = nnHi;
    *reinterpret_cast<f32x4*>(out + 3 * OUTQ + pbase)     = mnLo;
    *reinterpret_cast<f32x4*>(out + 3 * OUTQ + pbase + 4) = mnHi;
  }
}

extern "C" void kernel_launch(void* const* d_in, const int* in_sizes, int n_in,
                              void* d_out, int out_size, void* d_ws, size_t ws_size,
                              hipStream_t stream) {
  const float* x = (const float*)d_in[0];
  const float* h = (const float*)d_in[1];
  const float* c = (const float*)d_in[2];
  const float* n = (const float*)d_in[3];
  const float* m = (const float*)d_in[4];
  const float* W = (const float*)d_in[5];
  const float* r = (const float*)d_in[6];
  const float* b = (const float*)d_in[7];
  uint16_t* Bp = (uint16_t*)d_ws;   // 256 KB packed bf16 weights

  pack_weights<<<64, 256, 0, stream>>>(W, r, Bp);
  slstm_fused<<<NROWS / 64, 256, 0, stream>>>(x, h, c, n, m, b, Bp, (float*)d_out);
}